// Round 1
// baseline (719.798 us; speedup 1.0000x reference)
//
#include <hip/hip_runtime.h>

// K-Planes feature field: N=1M points, C=32 channels, 3 pairs, 3 resolutions.
// out[n, r*32 + c] = prod_p bilinear(plane[r][p][c], coords_p(n))
//
// Strategy:
//  - transpose planes (3,C,R,R) -> (3,R,R,C) into d_ws so the 32-channel
//    gather at each corner is one contiguous 128B segment (lane = channel).
//  - planes total 132 MB -> L3-resident; output streamed with nontemporal
//    stores to avoid evicting them.

constexpr int kN = 1048576;
constexpr int kC = 32;

// ---- transpose (3, C, R, R) -> (3, R, R, C), fully coalesced both sides ----
__global__ __launch_bounds__(1024) void kp_transpose(const float* __restrict__ in,
                                                     float* __restrict__ out, int R) {
    __shared__ float tile[32][33];
    const int tx = threadIdx.x;   // 0..31
    const int ty = threadIdx.y;   // 0..31
    const int x0 = blockIdx.x * 32;
    const int y  = blockIdx.y;
    const int p  = blockIdx.z;
    // read: in[((p*C + c)*R + y)*R + x], lanes sweep x -> coalesced
    tile[ty][tx] = in[(((size_t)p * kC + ty) * R + y) * R + x0 + tx];
    __syncthreads();
    // write: out[((p*R + y)*R + x)*C + c], lanes sweep c -> coalesced
    out[(((size_t)p * R + y) * R + x0 + ty) * kC + tx] = tile[tx][ty];
}

// ---- bilinear sample of one (pair, res) for channel c ----
template<int TRANS>
__device__ __forceinline__ float sample_one(const float* __restrict__ plane, int R, int c,
                                            float gx, float gy) {
    const float fr = (float)(R - 1);
    float ix = (gx + 1.0f) * 0.5f * fr;
    float iy = (gy + 1.0f) * 0.5f * fr;
    float x0f = fminf(fmaxf(floorf(ix), 0.0f), fr);
    float y0f = fminf(fmaxf(floorf(iy), 0.0f), fr);
    float wx = ix - x0f;
    float wy = iy - y0f;
    int xi0 = (int)x0f, yi0 = (int)y0f;
    int xi1 = min(xi0 + 1, R - 1);
    int yi1 = min(yi0 + 1, R - 1);
    float v00, v01, v10, v11;
    if (TRANS) {
        // channel-last: (y*R + x)*C + c ; 32 lanes (c) -> one 128B segment
        const float* r0 = plane + ((size_t)yi0 * R) * kC + c;
        const float* r1 = plane + ((size_t)yi1 * R) * kC + c;
        v00 = r0[(size_t)xi0 * kC];
        v01 = r0[(size_t)xi1 * kC];
        v10 = r1[(size_t)xi0 * kC];
        v11 = r1[(size_t)xi1 * kC];
    } else {
        // native: (c)*R*R + y*R + x  (fallback if ws too small)
        const float* pc = plane + (size_t)c * R * R;
        v00 = pc[yi0 * R + xi0];
        v01 = pc[yi0 * R + xi1];
        v10 = pc[yi1 * R + xi0];
        v11 = pc[yi1 * R + xi1];
    }
    float omx = 1.0f - wx, omy = 1.0f - wy;
    return v00 * omx * omy + v01 * wx * omy + v10 * omx * wy + v11 * wx * wy;
}

template<int TRANS>
__global__ __launch_bounds__(256) void kp_sample(const float* __restrict__ xs,
                                                 const float* __restrict__ p128,
                                                 const float* __restrict__ p256,
                                                 const float* __restrict__ p512,
                                                 float* __restrict__ out) {
    const int t = blockIdx.x * 256 + (int)threadIdx.x;
    const int n = t >> 5;        // point index (2 points per wave)
    const int c = t & 31;        // channel = lane within 32-group
    const float a = xs[n * 3 + 0];
    const float b = xs[n * 3 + 1];
    const float d = xs[n * 3 + 2];
    // PAIRS = (0,1),(0,2),(1,2); coords last dim = (gx, gy)
    const float gxs[3] = {a, a, b};
    const float gys[3] = {b, d, d};
    float* o = out + (size_t)n * 96;
    const float* planes[3] = {p128, p256, p512};
    const int Rs[3] = {128, 256, 512};
#pragma unroll
    for (int r = 0; r < 3; ++r) {
        const float* base = planes[r];
        const int R = Rs[r];
        float f = 1.0f;
#pragma unroll
        for (int p = 0; p < 3; ++p) {
            f *= sample_one<TRANS>(base + (size_t)p * R * R * kC, R, c, gxs[p], gys[p]);
        }
        // streaming store: don't let 402MB of output thrash L3's plane residency
        __builtin_nontemporal_store(f, o + r * 32 + c);
    }
}

extern "C" void kernel_launch(void* const* d_in, const int* in_sizes, int n_in,
                              void* d_out, int out_size, void* d_ws, size_t ws_size,
                              hipStream_t stream) {
    const float* xs   = (const float*)d_in[0];
    const float* p128 = (const float*)d_in[1];
    const float* p256 = (const float*)d_in[2];
    const float* p512 = (const float*)d_in[3];
    float* out = (float*)d_out;

    const size_t n128 = (size_t)3 * kC * 128 * 128;
    const size_t n256 = (size_t)3 * kC * 256 * 256;
    const size_t n512 = (size_t)3 * kC * 512 * 512;
    const size_t need = (n128 + n256 + n512) * sizeof(float);

    const int nblk = (kN * 32) / 256;  // 131072 blocks, 2 points per wave

    if (ws_size >= need) {
        float* t128 = (float*)d_ws;
        float* t256 = t128 + n128;
        float* t512 = t256 + n256;
        dim3 blk(32, 32);
        kp_transpose<<<dim3(128 / 32, 128, 3), blk, 0, stream>>>(p128, t128, 128);
        kp_transpose<<<dim3(256 / 32, 256, 3), blk, 0, stream>>>(p256, t256, 256);
        kp_transpose<<<dim3(512 / 32, 512, 3), blk, 0, stream>>>(p512, t512, 512);
        kp_sample<1><<<nblk, 256, 0, stream>>>(xs, t128, t256, t512, out);
    } else {
        kp_sample<0><<<nblk, 256, 0, stream>>>(xs, p128, p256, p512, out);
    }
}

// Round 2
// 436.390 us; speedup vs baseline: 1.6494x; 1.6494x over previous
//
#include <hip/hip_runtime.h>
#include <hip/hip_fp16.h>

// K-Planes feature field: N=1M points, C=32 channels, 3 pairs, 3 resolutions.
// out[n, r*32 + c] = prod_p bilinear(plane[r][p][c], coords_p(n))
//
// R1 strategy:
//  - planes transposed AND converted to fp16 channel-last (3,R,R,C) in d_ws:
//    each corner gather = one 64B contiguous segment; raw gather bytes halved.
//  - one sample kernel PER RESOLUTION: res128 fp16 = 3MB -> resident in each
//    XCD's 4MB L2 (gathers ~free); res256 = 12MB partial L2; res512 = 48MB L3.
//  - 8 lanes/point, 4 channels/lane (8B fp16 loads, float4 nt stores).

constexpr int kN = 1048576;
constexpr int kC = 32;

typedef float f32x4 __attribute__((ext_vector_type(4)));
typedef short s16x4 __attribute__((ext_vector_type(4)));

// ---- transpose+convert (3, C, R, R) fp32 -> (3, R, R, C) fp16 ----
__global__ __launch_bounds__(1024) void kp_transpose_h(const float* __restrict__ in,
                                                       __half* __restrict__ out, int R) {
    __shared__ float tile[32][33];
    const int tx = threadIdx.x;   // 0..31
    const int ty = threadIdx.y;   // 0..31
    const int x0 = blockIdx.x * 32;
    const int y  = blockIdx.y;
    const int p  = blockIdx.z;
    // read: in[((p*C + c)*R + y)*R + x], lanes sweep x -> coalesced
    tile[ty][tx] = in[(((size_t)p * kC + ty) * R + y) * R + x0 + tx];
    __syncthreads();
    // write: out[((p*R + y)*R + x)*C + c], lanes sweep c -> coalesced fp16
    out[(((size_t)p * R + y) * R + x0 + ty) * kC + tx] = __float2half_rn(tile[tx][ty]);
}

__device__ __forceinline__ void load4h(const __half* __restrict__ p, float* v) {
    union { s16x4 s; __half2 h[2]; } u;
    u.s = *reinterpret_cast<const s16x4*>(p);   // one 8B load
    float2 f01 = __half22float2(u.h[0]);
    float2 f23 = __half22float2(u.h[1]);
    v[0] = f01.x; v[1] = f01.y; v[2] = f23.x; v[3] = f23.y;
}

// ---- per-resolution sampler: 8 lanes/point, 4 ch/lane ----
template<int R>
__global__ __launch_bounds__(256) void kp_sample_h(const float* __restrict__ xs,
                                                   const __half* __restrict__ planes, // (3,R,R,C)
                                                   float* __restrict__ out, int rbase) {
    const int t = blockIdx.x * 256 + (int)threadIdx.x;
    const int n  = t >> 3;         // point index
    const int c4 = (t & 7) << 2;   // first of this lane's 4 channels
    const float a = xs[n * 3 + 0];
    const float b = xs[n * 3 + 1];
    const float d = xs[n * 3 + 2];
    // PAIRS = (0,1),(0,2),(1,2); coords last dim = (gx, gy)
    const float gx[3] = {a, a, b};
    const float gy[3] = {b, d, d};
    const float fr = (float)(R - 1);
    float f[4] = {1.f, 1.f, 1.f, 1.f};
#pragma unroll
    for (int p = 0; p < 3; ++p) {
        float ix = (gx[p] + 1.f) * 0.5f * fr;
        float iy = (gy[p] + 1.f) * 0.5f * fr;
        float x0f = fminf(fmaxf(floorf(ix), 0.f), fr);
        float y0f = fminf(fmaxf(floorf(iy), 0.f), fr);
        float wx = ix - x0f, wy = iy - y0f;
        int xi0 = (int)x0f, yi0 = (int)y0f;
        int xi1 = min(xi0 + 1, R - 1), yi1 = min(yi0 + 1, R - 1);
        const __half* pl = planes + (size_t)p * R * R * kC + c4;
        float v00[4], v01[4], v10[4], v11[4];
        load4h(pl + (yi0 * R + xi0) * kC, v00);
        load4h(pl + (yi0 * R + xi1) * kC, v01);
        load4h(pl + (yi1 * R + xi0) * kC, v10);
        load4h(pl + (yi1 * R + xi1) * kC, v11);
        float w00 = (1.f - wx) * (1.f - wy), w01 = wx * (1.f - wy);
        float w10 = (1.f - wx) * wy,         w11 = wx * wy;
#pragma unroll
        for (int j = 0; j < 4; ++j)
            f[j] *= w00 * v00[j] + w01 * v01[j] + w10 * v10[j] + w11 * v11[j];
    }
    f32x4 o = {f[0], f[1], f[2], f[3]};
    // streaming store: don't evict L2/L3-resident planes with 402MB of output
    __builtin_nontemporal_store(o, reinterpret_cast<f32x4*>(out + (size_t)n * 96 + rbase + c4));
}

// ---- fallback (ws too small): direct fp32 native-layout sampling ----
__global__ __launch_bounds__(256) void kp_sample_f32(const float* __restrict__ xs,
                                                     const float* __restrict__ p128,
                                                     const float* __restrict__ p256,
                                                     const float* __restrict__ p512,
                                                     float* __restrict__ out) {
    const int t = blockIdx.x * 256 + (int)threadIdx.x;
    const int n = t >> 5;
    const int c = t & 31;
    const float a = xs[n * 3 + 0], b = xs[n * 3 + 1], d = xs[n * 3 + 2];
    const float gxs[3] = {a, a, b};
    const float gys[3] = {b, d, d};
    const float* planes[3] = {p128, p256, p512};
    const int Rs[3] = {128, 256, 512};
    float* o = out + (size_t)n * 96;
#pragma unroll
    for (int r = 0; r < 3; ++r) {
        const int R = Rs[r];
        const float fr = (float)(R - 1);
        float f = 1.0f;
#pragma unroll
        for (int p = 0; p < 3; ++p) {
            float ix = (gxs[p] + 1.f) * 0.5f * fr;
            float iy = (gys[p] + 1.f) * 0.5f * fr;
            float x0f = fminf(fmaxf(floorf(ix), 0.f), fr);
            float y0f = fminf(fmaxf(floorf(iy), 0.f), fr);
            float wx = ix - x0f, wy = iy - y0f;
            int xi0 = (int)x0f, yi0 = (int)y0f;
            int xi1 = min(xi0 + 1, R - 1), yi1 = min(yi0 + 1, R - 1);
            const float* pc = planes[r] + ((size_t)p * kC + c) * R * R;
            float v00 = pc[yi0 * R + xi0], v01 = pc[yi0 * R + xi1];
            float v10 = pc[yi1 * R + xi0], v11 = pc[yi1 * R + xi1];
            f *= v00 * (1.f - wx) * (1.f - wy) + v01 * wx * (1.f - wy)
               + v10 * (1.f - wx) * wy + v11 * wx * wy;
        }
        __builtin_nontemporal_store(f, o + r * 32 + c);
    }
}

extern "C" void kernel_launch(void* const* d_in, const int* in_sizes, int n_in,
                              void* d_out, int out_size, void* d_ws, size_t ws_size,
                              hipStream_t stream) {
    const float* xs   = (const float*)d_in[0];
    const float* p128 = (const float*)d_in[1];
    const float* p256 = (const float*)d_in[2];
    const float* p512 = (const float*)d_in[3];
    float* out = (float*)d_out;

    const size_t n128 = (size_t)3 * 128 * 128 * kC;
    const size_t n256 = (size_t)3 * 256 * 256 * kC;
    const size_t n512 = (size_t)3 * 512 * 512 * kC;
    const size_t need = (n128 + n256 + n512) * sizeof(__half);

    if (ws_size >= need) {
        __half* t128 = (__half*)d_ws;
        __half* t256 = t128 + n128;
        __half* t512 = t256 + n256;
        dim3 blk(32, 32);
        kp_transpose_h<<<dim3(128 / 32, 128, 3), blk, 0, stream>>>(p128, t128, 128);
        kp_transpose_h<<<dim3(256 / 32, 256, 3), blk, 0, stream>>>(p256, t256, 256);
        kp_transpose_h<<<dim3(512 / 32, 512, 3), blk, 0, stream>>>(p512, t512, 512);
        const int nblk = (kN * 8) / 256;  // 32768 blocks, 8 points/wave
        kp_sample_h<128><<<nblk, 256, 0, stream>>>(xs, t128, out, 0);
        kp_sample_h<256><<<nblk, 256, 0, stream>>>(xs, t256, out, 32);
        kp_sample_h<512><<<nblk, 256, 0, stream>>>(xs, t512, out, 64);
    } else {
        kp_sample_f32<<<(kN * 32) / 256, 256, 0, stream>>>(xs, p128, p256, p512, out);
    }
}

// Round 3
// 341.380 us; speedup vs baseline: 2.1085x; 1.2783x over previous
//
#include <hip/hip_runtime.h>
#include <hip/hip_fp16.h>

// K-Planes feature field: N=1M points, C=32 channels, 3 pairs, 3 resolutions.
// out[n, r*32 + c] = prod_p bilinear(plane[r][p][c], coords_p(n))
//
// R2 strategy (on top of fp16 channel-last transposed planes):
//  - counting-sort points by 15-bit Morton cell (32^3) so consecutive blocks
//    sample tiny (~70KB) plane footprints -> gathers become L2 hits.
//  - XCD-swizzled sampler grid keeps sorted chunks on one XCD's L2.
//  - fused single sampler over all 3 resolutions (coords read once).

constexpr int kN = 1048576;
constexpr int kC = 32;
constexpr int kCells = 32 * 32 * 32;   // 15-bit Morton key

typedef float f32x4 __attribute__((ext_vector_type(4)));
typedef short s16x4 __attribute__((ext_vector_type(4)));

// ---- transpose+convert (3, C, R, R) fp32 -> (3, R, R, C) fp16 ----
__global__ __launch_bounds__(1024) void kp_transpose_h(const float* __restrict__ in,
                                                       __half* __restrict__ out, int R) {
    __shared__ float tile[32][33];
    const int tx = threadIdx.x, ty = threadIdx.y;
    const int x0 = blockIdx.x * 32;
    const int y  = blockIdx.y;
    const int p  = blockIdx.z;
    tile[ty][tx] = in[(((size_t)p * kC + ty) * R + y) * R + x0 + tx];
    __syncthreads();
    out[(((size_t)p * R + y) * R + x0 + ty) * kC + tx] = __float2half_rn(tile[tx][ty]);
}

// ---- Morton cell key from coords in [-1,1] ----
__device__ __forceinline__ unsigned cell_key(float x, float y, float z) {
    int cx = min(max((int)((x + 1.f) * 16.f), 0), 31);
    int cy = min(max((int)((y + 1.f) * 16.f), 0), 31);
    int cz = min(max((int)((z + 1.f) * 16.f), 0), 31);
    unsigned m = 0;
#pragma unroll
    for (int b = 0; b < 5; ++b) {
        m |= ((unsigned)((cx >> b) & 1)) << (3 * b);
        m |= ((unsigned)((cy >> b) & 1)) << (3 * b + 1);
        m |= ((unsigned)((cz >> b) & 1)) << (3 * b + 2);
    }
    return m;
}

__global__ __launch_bounds__(256) void kp_zero(unsigned* __restrict__ p, int n) {
    int i = blockIdx.x * 256 + threadIdx.x;
    if (i < n) p[i] = 0u;
}

__global__ __launch_bounds__(256) void kp_hist(const float* __restrict__ xs,
                                               unsigned* __restrict__ hist) {
    int n = blockIdx.x * 256 + threadIdx.x;
    float x = xs[n * 3 + 0], y = xs[n * 3 + 1], z = xs[n * 3 + 2];
    atomicAdd(&hist[cell_key(x, y, z)], 1u);
}

// single-block exclusive scan of kCells entries -> cursor
__global__ __launch_bounds__(1024) void kp_scan(const unsigned* __restrict__ hist,
                                                unsigned* __restrict__ cursor) {
    __shared__ unsigned sums[1024];
    const int t = threadIdx.x;
    const int per = kCells / 1024;          // 32
    unsigned local[32];
    unsigned s = 0;
    const int base = t * per;
#pragma unroll
    for (int i = 0; i < per; ++i) { local[i] = hist[base + i]; s += local[i]; }
    sums[t] = s;
    __syncthreads();
    for (int off = 1; off < 1024; off <<= 1) {
        unsigned v = (t >= off) ? sums[t - off] : 0u;
        __syncthreads();
        sums[t] += v;
        __syncthreads();
    }
    unsigned run = (t == 0) ? 0u : sums[t - 1];   // exclusive prefix
#pragma unroll
    for (int i = 0; i < per; ++i) { cursor[base + i] = run; run += local[i]; }
}

__global__ __launch_bounds__(256) void kp_scatter(const float* __restrict__ xs,
                                                  unsigned* __restrict__ cursor,
                                                  f32x4* __restrict__ sorted) {
    int n = blockIdx.x * 256 + threadIdx.x;
    float x = xs[n * 3 + 0], y = xs[n * 3 + 1], z = xs[n * 3 + 2];
    unsigned pos = atomicAdd(&cursor[cell_key(x, y, z)], 1u);
    f32x4 v = {x, y, z, __uint_as_float((unsigned)n)};
    sorted[pos] = v;
}

__device__ __forceinline__ void load4h(const __half* __restrict__ p, float* v) {
    union { s16x4 s; __half2 h[2]; } u;
    u.s = *reinterpret_cast<const s16x4*>(p);   // one 8B load
    float2 f01 = __half22float2(u.h[0]);
    float2 f23 = __half22float2(u.h[1]);
    v[0] = f01.x; v[1] = f01.y; v[2] = f23.x; v[3] = f23.y;
}

template<int R>
__device__ __forceinline__ void sample_res(const __half* __restrict__ planes, int c4,
                                           const float* gx, const float* gy, float* f) {
    const float fr = (float)(R - 1);
    f[0] = f[1] = f[2] = f[3] = 1.f;
#pragma unroll
    for (int p = 0; p < 3; ++p) {
        float ix = (gx[p] + 1.f) * 0.5f * fr;
        float iy = (gy[p] + 1.f) * 0.5f * fr;
        float x0f = fminf(fmaxf(floorf(ix), 0.f), fr);
        float y0f = fminf(fmaxf(floorf(iy), 0.f), fr);
        float wx = ix - x0f, wy = iy - y0f;
        int xi0 = (int)x0f, yi0 = (int)y0f;
        int xi1 = min(xi0 + 1, R - 1), yi1 = min(yi0 + 1, R - 1);
        const __half* pl = planes + (size_t)p * R * R * kC + c4;
        float v00[4], v01[4], v10[4], v11[4];
        load4h(pl + (yi0 * R + xi0) * kC, v00);
        load4h(pl + (yi0 * R + xi1) * kC, v01);
        load4h(pl + (yi1 * R + xi0) * kC, v10);
        load4h(pl + (yi1 * R + xi1) * kC, v11);
        float w00 = (1.f - wx) * (1.f - wy), w01 = wx * (1.f - wy);
        float w10 = (1.f - wx) * wy,         w11 = wx * wy;
#pragma unroll
        for (int j = 0; j < 4; ++j)
            f[j] *= w00 * v00[j] + w01 * v01[j] + w10 * v10[j] + w11 * v11[j];
    }
}

// ---- fused sampler over sorted points: 8 lanes/point, 4 ch/lane ----
__global__ __launch_bounds__(256) void kp_sample_sorted(const f32x4* __restrict__ pts,
                                                        const __half* __restrict__ t128,
                                                        const __half* __restrict__ t256,
                                                        const __half* __restrict__ t512,
                                                        float* __restrict__ out) {
    const int nwg = (kN * 8) / 256;                 // 32768, %8 == 0
    int bid = blockIdx.x;
    bid = (bid & 7) * (nwg / 8) + (bid >> 3);       // XCD-contiguous chunks
    const int li = threadIdx.x;
    const int n  = bid * 32 + (li >> 3);            // sorted point index
    const int c4 = (li & 7) << 2;
    f32x4 pt = pts[n];
    const float a = pt.x, b = pt.y, d = pt.z;
    const unsigned oi = __float_as_uint(pt.w);
    // PAIRS = (0,1),(0,2),(1,2); coords last dim = (gx, gy)
    const float gx[3] = {a, a, b};
    const float gy[3] = {b, d, d};
    float* o = out + (size_t)oi * 96 + c4;
    float f[4];
    sample_res<128>(t128, c4, gx, gy, f);
    __builtin_nontemporal_store(f32x4{f[0], f[1], f[2], f[3]}, (f32x4*)(o + 0));
    sample_res<256>(t256, c4, gx, gy, f);
    __builtin_nontemporal_store(f32x4{f[0], f[1], f[2], f[3]}, (f32x4*)(o + 32));
    sample_res<512>(t512, c4, gx, gy, f);
    __builtin_nontemporal_store(f32x4{f[0], f[1], f[2], f[3]}, (f32x4*)(o + 64));
}

// ---- unsorted per-res sampler (fallback if ws fits planes only) ----
template<int R>
__global__ __launch_bounds__(256) void kp_sample_h(const float* __restrict__ xs,
                                                   const __half* __restrict__ planes,
                                                   float* __restrict__ out, int rbase) {
    const int t = blockIdx.x * 256 + (int)threadIdx.x;
    const int n  = t >> 3;
    const int c4 = (t & 7) << 2;
    const float a = xs[n * 3 + 0], b = xs[n * 3 + 1], d = xs[n * 3 + 2];
    const float gx[3] = {a, a, b};
    const float gy[3] = {b, d, d};
    float f[4];
    sample_res<R>(planes, c4, gx, gy, f);
    __builtin_nontemporal_store(f32x4{f[0], f[1], f[2], f[3]},
                                (f32x4*)(out + (size_t)n * 96 + rbase + c4));
}

// ---- fp32 direct fallback (no ws) ----
__global__ __launch_bounds__(256) void kp_sample_f32(const float* __restrict__ xs,
                                                     const float* __restrict__ p128,
                                                     const float* __restrict__ p256,
                                                     const float* __restrict__ p512,
                                                     float* __restrict__ out) {
    const int t = blockIdx.x * 256 + (int)threadIdx.x;
    const int n = t >> 5;
    const int c = t & 31;
    const float a = xs[n * 3 + 0], b = xs[n * 3 + 1], d = xs[n * 3 + 2];
    const float gxs[3] = {a, a, b};
    const float gys[3] = {b, d, d};
    const float* planes[3] = {p128, p256, p512};
    const int Rs[3] = {128, 256, 512};
    float* o = out + (size_t)n * 96;
#pragma unroll
    for (int r = 0; r < 3; ++r) {
        const int R = Rs[r];
        const float fr = (float)(R - 1);
        float f = 1.0f;
#pragma unroll
        for (int p = 0; p < 3; ++p) {
            float ix = (gxs[p] + 1.f) * 0.5f * fr;
            float iy = (gys[p] + 1.f) * 0.5f * fr;
            float x0f = fminf(fmaxf(floorf(ix), 0.f), fr);
            float y0f = fminf(fmaxf(floorf(iy), 0.f), fr);
            float wx = ix - x0f, wy = iy - y0f;
            int xi0 = (int)x0f, yi0 = (int)y0f;
            int xi1 = min(xi0 + 1, R - 1), yi1 = min(yi0 + 1, R - 1);
            const float* pc = planes[r] + ((size_t)p * kC + c) * R * R;
            float v00 = pc[yi0 * R + xi0], v01 = pc[yi0 * R + xi1];
            float v10 = pc[yi1 * R + xi0], v11 = pc[yi1 * R + xi1];
            f *= v00 * (1.f - wx) * (1.f - wy) + v01 * wx * (1.f - wy)
               + v10 * (1.f - wx) * wy + v11 * wx * wy;
        }
        __builtin_nontemporal_store(f, o + r * 32 + c);
    }
}

extern "C" void kernel_launch(void* const* d_in, const int* in_sizes, int n_in,
                              void* d_out, int out_size, void* d_ws, size_t ws_size,
                              hipStream_t stream) {
    const float* xs   = (const float*)d_in[0];
    const float* p128 = (const float*)d_in[1];
    const float* p256 = (const float*)d_in[2];
    const float* p512 = (const float*)d_in[3];
    float* out = (float*)d_out;

    const size_t n128 = (size_t)3 * 128 * 128 * kC;
    const size_t n256 = (size_t)3 * 256 * 256 * kC;
    const size_t n512 = (size_t)3 * 512 * 512 * kC;
    const size_t planes_b = (n128 + n256 + n512) * sizeof(__half);
    const size_t sorted_b = (size_t)kN * 16;
    const size_t hist_b   = (size_t)kCells * 4;
    const size_t need_sorted = sorted_b + planes_b + 2 * hist_b + 256;
    const size_t need_plain  = planes_b;

    dim3 tblk(32, 32);
    const int nblk8 = (kN * 8) / 256;   // 32768

    if (ws_size >= need_sorted) {
        // ws layout: sorted (16B-aligned) | planes fp16 | hist | cursor
        f32x4* sorted = (f32x4*)d_ws;
        __half* t128 = (__half*)((char*)d_ws + sorted_b);
        __half* t256 = t128 + n128;
        __half* t512 = t256 + n256;
        unsigned* hist   = (unsigned*)((char*)d_ws + sorted_b + planes_b);
        unsigned* cursor = hist + kCells;

        kp_transpose_h<<<dim3(128 / 32, 128, 3), tblk, 0, stream>>>(p128, t128, 128);
        kp_transpose_h<<<dim3(256 / 32, 256, 3), tblk, 0, stream>>>(p256, t256, 256);
        kp_transpose_h<<<dim3(512 / 32, 512, 3), tblk, 0, stream>>>(p512, t512, 512);
        kp_zero<<<(kCells + 255) / 256, 256, 0, stream>>>(hist, kCells);
        kp_hist<<<kN / 256, 256, 0, stream>>>(xs, hist);
        kp_scan<<<1, 1024, 0, stream>>>(hist, cursor);
        kp_scatter<<<kN / 256, 256, 0, stream>>>(xs, cursor, sorted);
        kp_sample_sorted<<<nblk8, 256, 0, stream>>>(sorted, t128, t256, t512, out);
    } else if (ws_size >= need_plain) {
        __half* t128 = (__half*)d_ws;
        __half* t256 = t128 + n128;
        __half* t512 = t256 + n256;
        kp_transpose_h<<<dim3(128 / 32, 128, 3), tblk, 0, stream>>>(p128, t128, 128);
        kp_transpose_h<<<dim3(256 / 32, 256, 3), tblk, 0, stream>>>(p256, t256, 256);
        kp_transpose_h<<<dim3(512 / 32, 512, 3), tblk, 0, stream>>>(p512, t512, 512);
        kp_sample_h<128><<<nblk8, 256, 0, stream>>>(xs, t128, out, 0);
        kp_sample_h<256><<<nblk8, 256, 0, stream>>>(xs, t256, out, 32);
        kp_sample_h<512><<<nblk8, 256, 0, stream>>>(xs, t512, out, 64);
    } else {
        kp_sample_f32<<<(kN * 32) / 256, 256, 0, stream>>>(xs, p128, p256, p512, out);
    }
}